// Round 8
// baseline (476.062 us; speedup 1.0000x reference)
//
#include <hip/hip_runtime.h>
#include <hip/hip_bf16.h>
#include <math.h>

// Problem constants
#define B_  32
#define S_  512
#define H_  768
#define W_  128
#define G_  4
#define LW  129          // W+1
#define NH_ 4
#define HD_ 192
#define FF_ 2048
#define NL_ 2
#define NLAB_ 6
#define M_   (B_ * LW)   // 4128 rows of x
#define MPAD 4224        // 33 * 128 — zero GEMM bounds checks
#define EPS_ 1e-5f
#define SCALE_ 0.07216878364870323f   // 1/sqrt(192)

// attention padded dims
#define TP 192           // padded query rows per (b,h)
#define KP 160           // padded key count (mult of 32)
#define KR 144           // staged key rows (9 n-tiles)
#define KLD 200          // LDS row stride for K stage (bank-friendly)
#define PLD 168          // LDS row stride for P (bank-friendly for b128 frag reads)

#define QW_SZ (3 * H_ * H_)   // 1769472
#define OW_SZ (H_ * H_)       // 589824
#define F1_SZ (FF_ * H_)      // 1572864
#define F2_SZ (H_ * FF_)      // 1572864
#define WL_SZ (QW_SZ + OW_SZ + F1_SZ + F2_SZ)  // 5505024

typedef __bf16 bf16_8 __attribute__((ext_vector_type(8)));
typedef float  f32x4  __attribute__((ext_vector_type(4)));
typedef unsigned short ushort8_t __attribute__((ext_vector_type(8)));

__device__ __forceinline__ float b2f(unsigned short u) {
    union { unsigned int i; float f; } c; c.i = ((unsigned int)u) << 16; return c.f;
}
__device__ __forceinline__ unsigned short f2b(float f) {
    union { float f; unsigned int u; } c; c.f = f;
    unsigned int u = c.u;
    return (unsigned short)((u + 0x7FFFu + ((u >> 16) & 1u)) >> 16);   // RNE
}

// ---------------- reductions ----------------
__device__ __forceinline__ float wave_sum(float v) {
#pragma unroll
    for (int off = 1; off < 64; off <<= 1) v += __shfl_xor(v, off, 64);
    return v;
}
__device__ __forceinline__ float block_sum(float v, float* red) {
    v = wave_sum(v);
    int wid = threadIdx.x >> 6, lane = threadIdx.x & 63;
    if (lane == 0) red[wid] = v;
    __syncthreads();
    float r = (red[0] + red[1]) + (red[2] + red[3]);
    __syncthreads();
    return r;
}

// ---------------- gather + masked mean pool -> xb bf16 (incl. pad-row zeroing) ----------------
__global__ __launch_bounds__(256) void build_x_kernel(
    const float* __restrict__ hidden,   // (B,S,H)
    const int*   __restrict__ wti,      // (B,W,G)
    const int*   __restrict__ gmask,    // (B,W,G) bool as int32
    const int*   __restrict__ wvalid,   // (B,W)   bool as int32
    unsigned short* __restrict__ xb)    // (MPAD,H) bf16
{
    int t = blockIdx.x;     // 0..LW+2  (last 3 per batch: pad rows)
    int b = blockIdx.y;     // 0..B-1
    int tid = threadIdx.x;
    if (t >= LW) {
        int pr = M_ + b * 3 + (t - LW);
        size_t xo = (size_t)pr * H_;
#pragma unroll
        for (int i = 0; i < 3; i++) xb[xo + tid + i * 256] = 0;
        return;
    }
    size_t xo = ((size_t)b * LW + t) * H_;
    if (t == 0) {
        const float* src = hidden + (size_t)b * S_ * H_;   // token 0
#pragma unroll
        for (int i = 0; i < 3; i++) xb[xo + tid + i * 256] = f2b(src[tid + i * 256]);
    } else {
        int w = t - 1;
        int valid = wvalid[b * W_ + w];
        int ids[G_]; float msk[G_]; float cnt = 0.f;
#pragma unroll
        for (int g = 0; g < G_; g++) {
            ids[g] = wti[(b * W_ + w) * G_ + g];
            msk[g] = (gmask[(b * W_ + w) * G_ + g] != 0) ? 1.f : 0.f;
            cnt += msk[g];
        }
        float inv = valid ? (1.f / fmaxf(cnt, 1.f)) : 0.f;
#pragma unroll
        for (int i = 0; i < 3; i++) {
            int c = tid + i * 256;
            float a = 0.f;
#pragma unroll
            for (int g = 0; g < G_; g++)
                a += msk[g] * hidden[((size_t)b * S_ + ids[g]) * H_ + c];
            xb[xo + c] = f2b(a * inv);
        }
    }
}

// ---------------- weight fp32 -> bf16 (both layers, one kernel) ----------------
__global__ __launch_bounds__(256) void cvt_all_kernel(
    const float4* __restrict__ qw, const float4* __restrict__ ow,
    const float4* __restrict__ f1, const float4* __restrict__ f2,
    ushort4* __restrict__ dst)
{
    constexpr int WL4 = WL_SZ / 4;
    int i = blockIdx.x * 256 + threadIdx.x;   // 0 .. 2*WL4
    int l = (i < WL4) ? 0 : 1;
    int j = i - l * WL4;
    float4 v;
    if (j < QW_SZ / 4)                          v = qw[l * (QW_SZ / 4) + j];
    else if (j < (QW_SZ + OW_SZ) / 4)           v = ow[l * (OW_SZ / 4) + j - QW_SZ / 4];
    else if (j < (QW_SZ + OW_SZ + F1_SZ) / 4)   v = f1[l * (F1_SZ / 4) + j - (QW_SZ + OW_SZ) / 4];
    else                                        v = f2[l * (F2_SZ / 4) + j - (QW_SZ + OW_SZ + F1_SZ) / 4];
    ushort4 o; o.x = f2b(v.x); o.y = f2b(v.y); o.z = f2b(v.z); o.w = f2b(v.w);
    dst[i] = o;
}

// ---------------- LDS-staged bf16 MFMA GEMM (qkv / ff1 / ff2) ----------------
// XOR chunk swizzle (R6-verified) + XCD-band remap.
template <int BM, int BN, int BK, int RELU, int OUTBF, int SWZ>
__global__ __launch_bounds__(256) void gemm_mfma(
    const unsigned short* __restrict__ A,   // (MPAD,K) bf16
    const unsigned short* __restrict__ Bw,  // (N,K) bf16
    const float* __restrict__ bias,         // (N) f32
    void* __restrict__ Cout,                // (MPAD,N) f32 or bf16
    int N, int K)
{
    constexpr int MI  = BM / 32;
    constexpr int NJ  = BN / 32;
    constexpr int CPR = BK / 8;
    constexpr int RPL = 2048 / BK;
    constexpr int SA  = BM * BK / 2048;
    constexpr int SB  = BN * BK / 2048;

    __shared__ __align__(16) unsigned short As[BM * BK];
    __shared__ __align__(16) unsigned short Bs[BN * BK];

    const int tid  = threadIdx.x;
    const int lane = tid & 63;
    const int wid  = tid >> 6;

    int bx = blockIdx.x, by = blockIdx.y;
    if (SWZ) {
        int nx = gridDim.x;
        int total = nx * gridDim.y;              // must be % 8 == 0
        int id = by * nx + bx;
        int id2 = (id & 7) * (total >> 3) + (id >> 3);
        by = id2 / nx; bx = id2 - by * nx;
    }
    const int bm = by * BM;
    const int bn = bx * BN;

    const int wm = (wid & 1) * (BM / 2);
    const int wn = (wid >> 1) * (BN / 2);
    const int r  = lane & 15;
    const int q8 = lane >> 4;
    const int m8 = r & (CPR - 1);

    const int srow = tid / CPR;
    const int scol = (tid % CPR) ^ (srow & (CPR - 1));
    const unsigned short* Ag = A  + (size_t)(bm + srow) * K + scol * 8;
    const unsigned short* Bg = Bw + (size_t)(bn + srow) * K + scol * 8;

    const bf16_8* Af = (const bf16_8*)As;
    const bf16_8* Bf = (const bf16_8*)Bs;
    int arow[MI], brow[NJ];
#pragma unroll
    for (int i = 0; i < MI; i++) arow[i] = (wm + i * 16 + r) * CPR;
#pragma unroll
    for (int j = 0; j < NJ; j++) brow[j] = (wn + j * 16 + r) * CPR;

    f32x4 acc[MI][NJ];
#pragma unroll
    for (int i = 0; i < MI; i++)
#pragma unroll
        for (int j = 0; j < NJ; j++) acc[i][j] = (f32x4){0.f, 0.f, 0.f, 0.f};

    for (int k0 = 0; k0 < K; k0 += BK) {
#pragma unroll
        for (int s = 0; s < SA; s++)
            __builtin_amdgcn_global_load_lds(
                (const __attribute__((address_space(1))) void*)(Ag + (size_t)(s * RPL) * K + k0),
                (__attribute__((address_space(3))) void*)(As + s * 2048 + tid * 8), 16, 0, 0);
#pragma unroll
        for (int s = 0; s < SB; s++)
            __builtin_amdgcn_global_load_lds(
                (const __attribute__((address_space(1))) void*)(Bg + (size_t)(s * RPL) * K + k0),
                (__attribute__((address_space(3))) void*)(Bs + s * 2048 + tid * 8), 16, 0, 0);
        __syncthreads();
#pragma unroll
        for (int ks = 0; ks < BK / 32; ks++) {
            const int cc = (ks * 4 + q8) ^ m8;
            bf16_8 a[MI], b[NJ];
#pragma unroll
            for (int i = 0; i < MI; i++) a[i] = Af[arow[i] + cc];
#pragma unroll
            for (int j = 0; j < NJ; j++) b[j] = Bf[brow[j] + cc];
#pragma unroll
            for (int i = 0; i < MI; i++)
#pragma unroll
                for (int j = 0; j < NJ; j++)
                    acc[i][j] = __builtin_amdgcn_mfma_f32_16x16x32_bf16(a[i], b[j], acc[i][j], 0, 0, 0);
        }
        __syncthreads();
    }

    int col[NJ]; float bv[NJ];
#pragma unroll
    for (int j = 0; j < NJ; j++) { col[j] = bn + wn + j * 16 + r; bv[j] = bias[col[j]]; }
    const int row0 = bm + wm + ((lane >> 4) << 2);
#pragma unroll
    for (int i = 0; i < MI; i++) {
#pragma unroll
        for (int rg = 0; rg < 4; rg++) {
            size_t rowoff = (size_t)(row0 + i * 16 + rg) * N;
#pragma unroll
            for (int j = 0; j < NJ; j++) {
                float v = acc[i][j][rg] + bv[j];
                if (RELU) v = fmaxf(v, 0.f);
                if (OUTBF) ((unsigned short*)Cout)[rowoff + col[j]] = f2b(v);
                else       ((float*)Cout)[rowoff + col[j]] = v;
            }
        }
    }
}

// ---------------- direct-from-L2 GEMM (out-proj, K=768): no LDS, no barriers ----------------
// Block = 4 waves stacked in m (block tile 128m x 32n); wave tile 32m x 32n.
// Fragments loaded straight from global (L2-hot with XCD swizzle); compiler
// pipelines with fine-grained vmcnt — the structural barrier stall is gone.
__global__ __launch_bounds__(256) void gemm_direct(
    const unsigned short* __restrict__ A,   // (MPAD,K)
    const unsigned short* __restrict__ Bw,  // (N,K)
    const float* __restrict__ bias,
    unsigned short* __restrict__ Cout,      // (MPAD,N) bf16
    int N, int K)
{
    const int tid = threadIdx.x, lane = tid & 63, wid = tid >> 6;
    int bx = blockIdx.x, by = blockIdx.y;
    {   // XCD swizzle (grid % 8 == 0)
        int nx = gridDim.x, total = nx * gridDim.y;
        int id = by * nx + bx;
        int id2 = (id & 7) * (total >> 3) + (id >> 3);
        by = id2 / nx; bx = id2 - by * nx;
    }
    const int bm = by * 128 + wid * 32;
    const int bn = bx * 32;
    const int r = lane & 15, q8 = (lane >> 4) * 8;

    const unsigned short* Ap = A  + (size_t)(bm + r) * K + q8;
    const unsigned short* Bp = Bw + (size_t)(bn + r) * K + q8;
    const size_t row16 = (size_t)16 * K;

    f32x4 acc[2][2];
#pragma unroll
    for (int i = 0; i < 2; i++)
#pragma unroll
        for (int j = 0; j < 2; j++) acc[i][j] = (f32x4){0.f, 0.f, 0.f, 0.f};

#pragma unroll 4
    for (int k0 = 0; k0 < K; k0 += 32) {
        bf16_8 a0 = *(const bf16_8*)(Ap + k0);
        bf16_8 a1 = *(const bf16_8*)(Ap + row16 + k0);
        bf16_8 b0 = *(const bf16_8*)(Bp + k0);
        bf16_8 b1 = *(const bf16_8*)(Bp + row16 + k0);
        acc[0][0] = __builtin_amdgcn_mfma_f32_16x16x32_bf16(a0, b0, acc[0][0], 0, 0, 0);
        acc[0][1] = __builtin_amdgcn_mfma_f32_16x16x32_bf16(a0, b1, acc[0][1], 0, 0, 0);
        acc[1][0] = __builtin_amdgcn_mfma_f32_16x16x32_bf16(a1, b0, acc[1][0], 0, 0, 0);
        acc[1][1] = __builtin_amdgcn_mfma_f32_16x16x32_bf16(a1, b1, acc[1][1], 0, 0, 0);
    }

    int col[2]; float bv[2];
#pragma unroll
    for (int j = 0; j < 2; j++) { col[j] = bn + j * 16 + r; bv[j] = bias[col[j]]; }
    const int row0 = bm + ((lane >> 4) << 2);
#pragma unroll
    for (int i = 0; i < 2; i++) {
#pragma unroll
        for (int rg = 0; rg < 4; rg++) {
            size_t rowoff = (size_t)(row0 + i * 16 + rg) * N;
#pragma unroll
            for (int j = 0; j < 2; j++)
                Cout[rowoff + col[j]] = f2b(acc[i][j][rg] + bv[j]);
        }
    }
}

// ---------------- V transpose: qkvb V-third -> Vt[bh][192][KP] bf16 (zero-padded) ----------------
__global__ __launch_bounds__(256) void vt_kernel(
    const unsigned short* __restrict__ qkv,  // (MPAD, 3H)
    unsigned short* __restrict__ vtb)        // (128, HD_, KP)
{
    __shared__ __align__(16) unsigned short Vs[KR * KLD];
    int bh = blockIdx.x;
    int b = bh >> 2, h = bh & 3;
    int tid = threadIdx.x;
    for (int c = tid; c < KR * 24; c += 256) {
        int t = c / 24, j = c - t * 24;
        ushort8_t v = (ushort8_t){0,0,0,0,0,0,0,0};
        if (t < LW)
            v = *(const ushort8_t*)(qkv + (size_t)(b * LW + t) * (3 * H_) + 2 * H_ + h * HD_ + j * 8);
        *(ushort8_t*)(&Vs[t * KLD + j * 8]) = v;
    }
    __syncthreads();
    size_t obase = (size_t)bh * (HD_ * KP);
    for (int c = tid; c < HD_ * (KP / 4); c += 256) {
        int d = c / (KP / 4), t0 = (c - d * (KP / 4)) * 4;
        ushort4 o;
        o.x = (t0 + 0 < KR) ? Vs[(t0 + 0) * KLD + d] : 0;
        o.y = (t0 + 1 < KR) ? Vs[(t0 + 1) * KLD + d] : 0;
        o.z = (t0 + 2 < KR) ? Vs[(t0 + 2) * KLD + d] : 0;
        o.w = (t0 + 3 < KR) ? Vs[(t0 + 3) * KLD + d] : 0;
        *(ushort4*)(&vtb[obase + (size_t)d * KP + t0]) = o;
    }
}

// ---------------- fused scores+softmax+PV: P stays in LDS ----------------
// grid (3, 128). Phase 1: QK^T + softmax -> Ps (LDS, stride PLD). Phase 2: P@V^T
// with A-frags from LDS, B-frags (Vt) from global/L2.
__global__ __launch_bounds__(256) void attn_fused_kernel(
    const unsigned short* __restrict__ qkv,   // (MPAD, 3H)
    const int*            __restrict__ wvalid,
    const unsigned short* __restrict__ vtb,   // (128, HD_, KP)
    unsigned short*       __restrict__ ctx)   // (MPAD, H)
{
    __shared__ __align__(16) unsigned short Ks[KR * KLD];
    __shared__ __align__(16) unsigned short Ps[64 * PLD];
    __shared__ float msk[KR];
    int mb = blockIdx.x;          // 0..2
    int bh = blockIdx.y;
    int b = bh >> 2, h = bh & 3;
    int tid = threadIdx.x, lane = tid & 63, wid = tid >> 6;
    int q = lane >> 4, r = lane & 15;

    for (int c = tid; c < KR * 24; c += 256) {
        int t = c / 24, j = c - t * 24;
        ushort8_t v = (ushort8_t){0,0,0,0,0,0,0,0};
        if (t < LW)
            v = *(const ushort8_t*)(qkv + (size_t)(b * LW + t) * (3 * H_) + H_ + h * HD_ + j * 8);
        *(ushort8_t*)(&Ks[t * KLD + j * 8]) = v;
    }
    if (tid < KR) {
        bool valid = (tid == 0) || (tid <= W_ && wvalid[b * W_ + tid - 1] != 0);
        msk[tid] = valid ? 0.f : -1e30f;
    }
    __syncthreads();

    // ---- phase 1: scores + softmax, one 16-row tile per wave ----
    const int lrow0 = wid * 16;                   // local P row base
    const unsigned short* Qp = qkv + ((size_t)(b * LW) + mb * 64 + lrow0 + r) * (3 * H_) + h * HD_;

    f32x4 acc[9];
#pragma unroll
    for (int nt = 0; nt < 9; nt++) acc[nt] = (f32x4){0.f, 0.f, 0.f, 0.f};
    for (int ks = 0; ks < HD_ / 32; ks++) {
        bf16_8 a = *(const bf16_8*)(Qp + ks * 32 + q * 8);
#pragma unroll
        for (int nt = 0; nt < 9; nt++) {
            bf16_8 bfrag = *(const bf16_8*)(&Ks[(nt * 16 + r) * KLD + ks * 32 + q * 8]);
            acc[nt] = __builtin_amdgcn_mfma_f32_16x16x32_bf16(a, bfrag, acc[nt], 0, 0, 0);
        }
    }
    float mk[9];
#pragma unroll
    for (int nt = 0; nt < 9; nt++) mk[nt] = msk[nt * 16 + r];
#pragma unroll
    for (int rg = 0; rg < 4; rg++) {
        float v[9]; float mx = -1e30f;
#pragma unroll
        for (int nt = 0; nt < 9; nt++) { v[nt] = acc[nt][rg] * SCALE_ + mk[nt]; mx = fmaxf(mx, v[nt]); }
#pragma unroll
        for (int off = 1; off < 16; off <<= 1) mx = fmaxf(mx, __shfl_xor(mx, off, 64));
        float s = 0.f;
#pragma unroll
        for (int nt = 0; nt < 9; nt++) { v[nt] = __expf(v[nt] - mx); s += v[nt]; }
#pragma unroll
        for (int off = 1; off < 16; off <<= 1) s += __shfl_xor(s, off, 64);
        float inv = 1.f / s;
        int lr = lrow0 + q * 4 + rg;
#pragma unroll
        for (int nt = 0; nt < 9; nt++)
            Ps[lr * PLD + nt * 16 + r] = f2b(v[nt] * inv);
        Ps[lr * PLD + KR + r] = 0;   // zero pad cols 144..159
    }
    __syncthreads();

    // ---- phase 2: ctx = P @ V^T; waves 2m x 2n (32m x 96n each) ----
    const int wm = (wid & 1) * 32, wn = (wid >> 1) * 96;
    size_t vbase = (size_t)bh * (HD_ * KP);

    f32x4 pacc[2][6];
#pragma unroll
    for (int i = 0; i < 2; i++)
#pragma unroll
        for (int j = 0; j < 6; j++) pacc[i][j] = (f32x4){0.f, 0.f, 0.f, 0.f};

    for (int ks = 0; ks < KP / 32; ks++) {
        bf16_8 a[2], bb[6];
#pragma unroll
        for (int i = 0; i < 2; i++)
            a[i] = *(const bf16_8*)(&Ps[(wm + i * 16 + r) * PLD + ks * 32 + q * 8]);
#pragma unroll
        for (int j = 0; j < 6; j++)
            bb[j] = *(const bf16_8*)(vtb + vbase + (size_t)(wn + j * 16 + r) * KP + ks * 32 + q * 8);
#pragma unroll
        for (int i = 0; i < 2; i++)
#pragma unroll
            for (int j = 0; j < 6; j++)
                pacc[i][j] = __builtin_amdgcn_mfma_f32_16x16x32_bf16(a[i], bb[j], pacc[i][j], 0, 0, 0);
    }

#pragma unroll
    for (int i = 0; i < 2; i++) {
#pragma unroll
        for (int rg = 0; rg < 4; rg++) {
            int tl = mb * 64 + wm + i * 16 + q * 4 + rg;
            if (tl < LW) {
                size_t rowoff = (size_t)(b * LW + tl) * H_ + h * HD_;
#pragma unroll
                for (int j = 0; j < 6; j++)
                    ctx[rowoff + wn + j * 16 + r] = f2b(pacc[i][j][rg]);
            }
        }
    }
}

// ---------------- fused residual add + LayerNorm (pure bf16 stream, f32 math) ----------------
__global__ __launch_bounds__(256) void add_ln_kernel(
    unsigned short* __restrict__ xb, const unsigned short* __restrict__ res,
    const float* __restrict__ sc, const float* __restrict__ bi)
{
    __shared__ float red[4];
    int row = blockIdx.x;
    int tid = threadIdx.x;
    size_t base = (size_t)row * H_;
    float v[3];
    float sum = 0.f;
#pragma unroll
    for (int i = 0; i < 3; i++) {
        int c = tid + i * 256;
        float t = b2f(xb[base + c]) + b2f(res[base + c]);
        v[i] = t; sum += t;
    }
    sum = block_sum(sum, red);
    float mean = sum * (1.f / H_);
    float var = 0.f;
#pragma unroll
    for (int i = 0; i < 3; i++) { float d = v[i] - mean; var += d * d; }
    var = block_sum(var, red);
    float inv = rsqrtf(var * (1.f / H_) + EPS_);
#pragma unroll
    for (int i = 0; i < 3; i++) {
        int c = tid + i * 256;
        xb[base + c] = f2b((v[i] - mean) * inv * sc[c] + bi[c]);
    }
}

// ---------------- classifier + pooled copy (32 blocks x 6 waves, bf16 in) ----------------
__global__ __launch_bounds__(384) void cls_kernel(
    const unsigned short* __restrict__ xb,
    const float* __restrict__ cls_w, const float* __restrict__ cls_b,
    float* __restrict__ out)
{
    int b = blockIdx.x;
    int tid = threadIdx.x;
    const unsigned short* p = &xb[((size_t)b * LW) * H_];
    for (int c = tid; c < H_; c += 384) out[B_ * NLAB_ + b * H_ + c] = b2f(p[c]);
    int w = tid >> 6, lane = tid & 63;
    if (w < NLAB_) {
        const float* wv = &cls_w[w * H_];
        float acc = 0.f;
#pragma unroll
        for (int i = 0; i < H_ / 64; i++) {
            int c = lane + i * 64;
            acc += b2f(p[c]) * wv[c];
        }
        acc = wave_sum(acc);
        if (lane == 0) out[b * NLAB_ + w] = acc + cls_b[w];
    }
}

extern "C" void kernel_launch(void* const* d_in, const int* in_sizes, int n_in,
                              void* d_out, int out_size, void* d_ws, size_t ws_size,
                              hipStream_t stream) {
    const float* hidden = (const float*)d_in[0];
    const int*   wti    = (const int*)d_in[1];
    const int*   gmask  = (const int*)d_in[2];
    const int*   wvalid = (const int*)d_in[3];
    const float* qkv_w  = (const float*)d_in[4];
    const float* qkv_b  = (const float*)d_in[5];
    const float* out_w  = (const float*)d_in[6];
    const float* out_b  = (const float*)d_in[7];
    const float* ff1_w  = (const float*)d_in[8];
    const float* ff1_b  = (const float*)d_in[9];
    const float* ff2_w  = (const float*)d_in[10];
    const float* ff2_b  = (const float*)d_in[11];
    const float* ln1_s  = (const float*)d_in[12];
    const float* ln1_b  = (const float*)d_in[13];
    const float* ln2_s  = (const float*)d_in[14];
    const float* ln2_b  = (const float*)d_in[15];
    const float* cls_w  = (const float*)d_in[16];
    const float* cls_b  = (const float*)d_in[17];
    float* out = (float*)d_out;

    // workspace (all bf16): ~62 MB
    const size_t XSZ = (size_t)MPAD * H_;             // 3,244,032
    const size_t ASZ = (size_t)128 * TP * KP;         // 3,932,160
    unsigned short* U    = (unsigned short*)d_ws;     // ASZ region: vtb during attn; tmpb after
    unsigned short* vtb  = U;
    unsigned short* tmpb = U;                         // lifetimes disjoint
    unsigned short* xb   = U + ASZ;                   // XSZ
    unsigned short* ctxb = xb + XSZ;                  // XSZ
    unsigned short* qkvb = ctxb + XSZ;                // 3*XSZ (aliased: h1 MPAD*FF)
    unsigned short* wb   = qkvb + (size_t)MPAD * 3 * H_;     // 2*WL_SZ (both layers)

    build_x_kernel<<<dim3(LW + 3, B_), 256, 0, stream>>>(hidden, wti, gmask, wvalid, xb);
    cvt_all_kernel<<<2 * WL_SZ / 4 / 256, 256, 0, stream>>>(
        (const float4*)qkv_w, (const float4*)out_w,
        (const float4*)ff1_w, (const float4*)ff2_w, (ushort4*)wb);

    const int GM = MPAD / 64;   // 66 m-blocks
    for (int l = 0; l < NL_; l++) {
        unsigned short* wbl = wb + (size_t)l * WL_SZ;
        // qkv = x @ qkv_w^T + b -> bf16
        gemm_mfma<64, 128, 64, 0, 1, 0><<<dim3(3 * H_ / 128, GM), 256, 0, stream>>>(
            xb, wbl, qkv_b + (size_t)l * 3 * H_, qkvb, 3 * H_, H_);
        // attention: V-transpose, fused scores+softmax+PV
        vt_kernel<<<128, 256, 0, stream>>>(qkvb, vtb);
        attn_fused_kernel<<<dim3(3, 128), 256, 0, stream>>>(qkvb, wvalid, vtb, ctxb);
        // attn out-proj -> bf16 tmp (direct-from-L2, no barriers; 24x33=792 blocks %8 ok)
        gemm_direct<<<dim3(H_ / 32, MPAD / 128), 256, 0, stream>>>(
            ctxb, wbl + QW_SZ, out_b + (size_t)l * H_, tmpb, H_, H_);
        add_ln_kernel<<<M_, 256, 0, stream>>>(xb, tmpb,
            ln1_s + (size_t)l * H_, ln1_b + (size_t)l * H_);
        // h1 = relu(x @ ff1_w^T + b) -> bf16
        gemm_mfma<64, 128, 64, 1, 1, 1><<<dim3(FF_ / 128, GM), 256, 0, stream>>>(
            xb, wbl + QW_SZ + OW_SZ, ff1_b + (size_t)l * FF_, qkvb, FF_, H_);
        // ff2 -> bf16 tmp (K=2048: LDS version keeps traffic halved)
        gemm_mfma<64, 64, 64, 0, 1, 1><<<dim3(H_ / 64, GM), 256, 0, stream>>>(
            qkvb, wbl + QW_SZ + OW_SZ + F1_SZ, ff2_b + (size_t)l * H_, tmpb, H_, FF_);
        add_ln_kernel<<<M_, 256, 0, stream>>>(xb, tmpb,
            ln2_s + (size_t)l * H_, ln2_b + (size_t)l * H_);
    }
    cls_kernel<<<B_, 384, 0, stream>>>(xb, cls_w, cls_b, out);
    (void)in_sizes; (void)n_in; (void)out_size; (void)ws_size;
}

// Round 9
// 434.220 us; speedup vs baseline: 1.0964x; 1.0964x over previous
//
#include <hip/hip_runtime.h>
#include <hip/hip_bf16.h>
#include <math.h>

// Problem constants
#define B_  32
#define S_  512
#define H_  768
#define W_  128
#define G_  4
#define LW  129          // W+1
#define NH_ 4
#define HD_ 192
#define FF_ 2048
#define NL_ 2
#define NLAB_ 6
#define M_   (B_ * LW)   // 4128 rows of x
#define MPAD 4224        // 33 * 128 — zero GEMM bounds checks
#define EPS_ 1e-5f
#define SCALE_ 0.07216878364870323f   // 1/sqrt(192)

// attention padded dims
#define TP 192           // padded query rows per (b,h)
#define KP 160           // padded key count (mult of 32)
#define KR 144           // staged key rows (9 n-tiles)
#define KLD 200          // LDS row stride for K stage (bank-friendly)
#define PLD 168          // LDS row stride for P (bank-friendly for b128 frag reads)

#define QW_SZ (3 * H_ * H_)   // 1769472
#define OW_SZ (H_ * H_)       // 589824
#define F1_SZ (FF_ * H_)      // 1572864
#define F2_SZ (H_ * FF_)      // 1572864
#define WL_SZ (QW_SZ + OW_SZ + F1_SZ + F2_SZ)  // 5505024

typedef __bf16 bf16_8 __attribute__((ext_vector_type(8)));
typedef float  f32x4  __attribute__((ext_vector_type(4)));
typedef unsigned short ushort8_t __attribute__((ext_vector_type(8)));

__device__ __forceinline__ float b2f(unsigned short u) {
    union { unsigned int i; float f; } c; c.i = ((unsigned int)u) << 16; return c.f;
}
__device__ __forceinline__ unsigned short f2b(float f) {
    union { float f; unsigned int u; } c; c.f = f;
    unsigned int u = c.u;
    return (unsigned short)((u + 0x7FFFu + ((u >> 16) & 1u)) >> 16);   // RNE
}

// ---------------- reductions ----------------
__device__ __forceinline__ float wave_sum(float v) {
#pragma unroll
    for (int off = 1; off < 64; off <<= 1) v += __shfl_xor(v, off, 64);
    return v;
}
__device__ __forceinline__ float block_sum(float v, float* red) {
    v = wave_sum(v);
    int wid = threadIdx.x >> 6, lane = threadIdx.x & 63;
    if (lane == 0) red[wid] = v;
    __syncthreads();
    float r = (red[0] + red[1]) + (red[2] + red[3]);
    __syncthreads();
    return r;
}

// ---------------- gather + masked mean pool -> xb bf16 (incl. pad-row zeroing) ----------------
__global__ __launch_bounds__(256) void build_x_kernel(
    const float* __restrict__ hidden,   // (B,S,H)
    const int*   __restrict__ wti,      // (B,W,G)
    const int*   __restrict__ gmask,    // (B,W,G) bool as int32
    const int*   __restrict__ wvalid,   // (B,W)   bool as int32
    unsigned short* __restrict__ xb)    // (MPAD,H) bf16
{
    int t = blockIdx.x;     // 0..LW+2  (last 3 per batch: pad rows)
    int b = blockIdx.y;     // 0..B-1
    int tid = threadIdx.x;
    if (t >= LW) {
        int pr = M_ + b * 3 + (t - LW);
        size_t xo = (size_t)pr * H_;
#pragma unroll
        for (int i = 0; i < 3; i++) xb[xo + tid + i * 256] = 0;
        return;
    }
    size_t xo = ((size_t)b * LW + t) * H_;
    if (t == 0) {
        const float* src = hidden + (size_t)b * S_ * H_;   // token 0
#pragma unroll
        for (int i = 0; i < 3; i++) xb[xo + tid + i * 256] = f2b(src[tid + i * 256]);
    } else {
        int w = t - 1;
        int valid = wvalid[b * W_ + w];
        int ids[G_]; float msk[G_]; float cnt = 0.f;
#pragma unroll
        for (int g = 0; g < G_; g++) {
            ids[g] = wti[(b * W_ + w) * G_ + g];
            msk[g] = (gmask[(b * W_ + w) * G_ + g] != 0) ? 1.f : 0.f;
            cnt += msk[g];
        }
        float inv = valid ? (1.f / fmaxf(cnt, 1.f)) : 0.f;
#pragma unroll
        for (int i = 0; i < 3; i++) {
            int c = tid + i * 256;
            float a = 0.f;
#pragma unroll
            for (int g = 0; g < G_; g++)
                a += msk[g] * hidden[((size_t)b * S_ + ids[g]) * H_ + c];
            xb[xo + c] = f2b(a * inv);
        }
    }
}

// ---------------- weight fp32 -> bf16 (both layers, one kernel) ----------------
__global__ __launch_bounds__(256) void cvt_all_kernel(
    const float4* __restrict__ qw, const float4* __restrict__ ow,
    const float4* __restrict__ f1, const float4* __restrict__ f2,
    ushort4* __restrict__ dst)
{
    constexpr int WL4 = WL_SZ / 4;
    int i = blockIdx.x * 256 + threadIdx.x;   // 0 .. 2*WL4
    int l = (i < WL4) ? 0 : 1;
    int j = i - l * WL4;
    float4 v;
    if (j < QW_SZ / 4)                          v = qw[l * (QW_SZ / 4) + j];
    else if (j < (QW_SZ + OW_SZ) / 4)           v = ow[l * (OW_SZ / 4) + j - QW_SZ / 4];
    else if (j < (QW_SZ + OW_SZ + F1_SZ) / 4)   v = f1[l * (F1_SZ / 4) + j - (QW_SZ + OW_SZ) / 4];
    else                                        v = f2[l * (F2_SZ / 4) + j - (QW_SZ + OW_SZ + F1_SZ) / 4];
    ushort4 o; o.x = f2b(v.x); o.y = f2b(v.y); o.z = f2b(v.z); o.w = f2b(v.w);
    dst[i] = o;
}

// ---------------- LDS-staged bf16 MFMA GEMM ----------------
// XOR chunk swizzle (R6-verified) + generic XCD-band remap (round-robin deal
// bijection: band=id%8 gets a contiguous output band — works for any grid size).
template <int BM, int BN, int BK, int RELU, int OUTBF, int SWZ>
__global__ __launch_bounds__(256) void gemm_mfma(
    const unsigned short* __restrict__ A,   // (MPAD,K) bf16
    const unsigned short* __restrict__ Bw,  // (N,K) bf16
    const float* __restrict__ bias,         // (N) f32
    void* __restrict__ Cout,                // (MPAD,N) f32 or bf16
    int N, int K)
{
    constexpr int MI  = BM / 32;
    constexpr int NJ  = BN / 32;
    constexpr int CPR = BK / 8;
    constexpr int RPL = 2048 / BK;
    constexpr int SA  = BM * BK / 2048;
    constexpr int SB  = BN * BK / 2048;

    __shared__ __align__(16) unsigned short As[BM * BK];
    __shared__ __align__(16) unsigned short Bs[BN * BK];

    const int tid  = threadIdx.x;
    const int lane = tid & 63;
    const int wid  = tid >> 6;

    int bx = blockIdx.x, by = blockIdx.y;
    if (SWZ) {
        int nx = gridDim.x;
        int total = nx * gridDim.y;
        int id = by * nx + bx;
        int qd = total >> 3, rb = total & 7;
        int band = id & 7, pos = id >> 3;
        int id2 = band * qd + ((band < rb) ? band : rb) + pos;
        by = id2 / nx; bx = id2 - by * nx;
    }
    const int bm = by * BM;
    const int bn = bx * BN;

    const int wm = (wid & 1) * (BM / 2);
    const int wn = (wid >> 1) * (BN / 2);
    const int r  = lane & 15;
    const int q8 = lane >> 4;
    const int m8 = r & (CPR - 1);

    const int srow = tid / CPR;
    const int scol = (tid % CPR) ^ (srow & (CPR - 1));
    const unsigned short* Ag = A  + (size_t)(bm + srow) * K + scol * 8;
    const unsigned short* Bg = Bw + (size_t)(bn + srow) * K + scol * 8;

    const bf16_8* Af = (const bf16_8*)As;
    const bf16_8* Bf = (const bf16_8*)Bs;
    int arow[MI], brow[NJ];
#pragma unroll
    for (int i = 0; i < MI; i++) arow[i] = (wm + i * 16 + r) * CPR;
#pragma unroll
    for (int j = 0; j < NJ; j++) brow[j] = (wn + j * 16 + r) * CPR;

    f32x4 acc[MI][NJ];
#pragma unroll
    for (int i = 0; i < MI; i++)
#pragma unroll
        for (int j = 0; j < NJ; j++) acc[i][j] = (f32x4){0.f, 0.f, 0.f, 0.f};

    for (int k0 = 0; k0 < K; k0 += BK) {
#pragma unroll
        for (int s = 0; s < SA; s++)
            __builtin_amdgcn_global_load_lds(
                (const __attribute__((address_space(1))) void*)(Ag + (size_t)(s * RPL) * K + k0),
                (__attribute__((address_space(3))) void*)(As + s * 2048 + tid * 8), 16, 0, 0);
#pragma unroll
        for (int s = 0; s < SB; s++)
            __builtin_amdgcn_global_load_lds(
                (const __attribute__((address_space(1))) void*)(Bg + (size_t)(s * RPL) * K + k0),
                (__attribute__((address_space(3))) void*)(Bs + s * 2048 + tid * 8), 16, 0, 0);
        __syncthreads();
#pragma unroll
        for (int ks = 0; ks < BK / 32; ks++) {
            const int cc = (ks * 4 + q8) ^ m8;
            bf16_8 a[MI], b[NJ];
#pragma unroll
            for (int i = 0; i < MI; i++) a[i] = Af[arow[i] + cc];
#pragma unroll
            for (int j = 0; j < NJ; j++) b[j] = Bf[brow[j] + cc];
#pragma unroll
            for (int i = 0; i < MI; i++)
#pragma unroll
                for (int j = 0; j < NJ; j++)
                    acc[i][j] = __builtin_amdgcn_mfma_f32_16x16x32_bf16(a[i], b[j], acc[i][j], 0, 0, 0);
        }
        __syncthreads();
    }

    int col[NJ]; float bv[NJ];
#pragma unroll
    for (int j = 0; j < NJ; j++) { col[j] = bn + wn + j * 16 + r; bv[j] = bias[col[j]]; }
    const int row0 = bm + wm + ((lane >> 4) << 2);
#pragma unroll
    for (int i = 0; i < MI; i++) {
#pragma unroll
        for (int rg = 0; rg < 4; rg++) {
            size_t rowoff = (size_t)(row0 + i * 16 + rg) * N;
#pragma unroll
            for (int j = 0; j < NJ; j++) {
                float v = acc[i][j][rg] + bv[j];
                if (RELU) v = fmaxf(v, 0.f);
                if (OUTBF) ((unsigned short*)Cout)[rowoff + col[j]] = f2b(v);
                else       ((float*)Cout)[rowoff + col[j]] = v;
            }
        }
    }
}

// ---------------- V transpose: qkvb V-third -> Vt[bh][192][KP] bf16 (zero-padded) ----------------
__global__ __launch_bounds__(256) void vt_kernel(
    const unsigned short* __restrict__ qkv,  // (MPAD, 3H)
    unsigned short* __restrict__ vtb)        // (128, HD_, KP)
{
    __shared__ __align__(16) unsigned short Vs[KR * KLD];
    int bh = blockIdx.x;
    int b = bh >> 2, h = bh & 3;
    int tid = threadIdx.x;
    for (int c = tid; c < KR * 24; c += 256) {
        int t = c / 24, j = c - t * 24;
        ushort8_t v = (ushort8_t){0,0,0,0,0,0,0,0};
        if (t < LW)
            v = *(const ushort8_t*)(qkv + (size_t)(b * LW + t) * (3 * H_) + 2 * H_ + h * HD_ + j * 8);
        *(ushort8_t*)(&Vs[t * KLD + j * 8]) = v;
    }
    __syncthreads();
    size_t obase = (size_t)bh * (HD_ * KP);
    for (int c = tid; c < HD_ * (KP / 4); c += 256) {
        int d = c / (KP / 4), t0 = (c - d * (KP / 4)) * 4;
        ushort4 o;
        o.x = (t0 + 0 < KR) ? Vs[(t0 + 0) * KLD + d] : 0;
        o.y = (t0 + 1 < KR) ? Vs[(t0 + 1) * KLD + d] : 0;
        o.z = (t0 + 2 < KR) ? Vs[(t0 + 2) * KLD + d] : 0;
        o.w = (t0 + 3 < KR) ? Vs[(t0 + 3) * KLD + d] : 0;
        *(ushort4*)(&vtb[obase + (size_t)d * KP + t0]) = o;
    }
}

// ---------------- fused scores+softmax+PV: P stays in LDS ----------------
__global__ __launch_bounds__(256) void attn_fused_kernel(
    const unsigned short* __restrict__ qkv,   // (MPAD, 3H)
    const int*            __restrict__ wvalid,
    const unsigned short* __restrict__ vtb,   // (128, HD_, KP)
    unsigned short*       __restrict__ ctx)   // (MPAD, H)
{
    __shared__ __align__(16) unsigned short Ks[KR * KLD];
    __shared__ __align__(16) unsigned short Ps[64 * PLD];
    __shared__ float msk[KR];
    int mb = blockIdx.x;          // 0..2
    int bh = blockIdx.y;
    int b = bh >> 2, h = bh & 3;
    int tid = threadIdx.x, lane = tid & 63, wid = tid >> 6;
    int q = lane >> 4, r = lane & 15;

    for (int c = tid; c < KR * 24; c += 256) {
        int t = c / 24, j = c - t * 24;
        ushort8_t v = (ushort8_t){0,0,0,0,0,0,0,0};
        if (t < LW)
            v = *(const ushort8_t*)(qkv + (size_t)(b * LW + t) * (3 * H_) + H_ + h * HD_ + j * 8);
        *(ushort8_t*)(&Ks[t * KLD + j * 8]) = v;
    }
    if (tid < KR) {
        bool valid = (tid == 0) || (tid <= W_ && wvalid[b * W_ + tid - 1] != 0);
        msk[tid] = valid ? 0.f : -1e30f;
    }
    __syncthreads();

    // ---- phase 1: scores + softmax, one 16-row tile per wave ----
    const int lrow0 = wid * 16;
    const unsigned short* Qp = qkv + ((size_t)(b * LW) + mb * 64 + lrow0 + r) * (3 * H_) + h * HD_;

    f32x4 acc[9];
#pragma unroll
    for (int nt = 0; nt < 9; nt++) acc[nt] = (f32x4){0.f, 0.f, 0.f, 0.f};
    for (int ks = 0; ks < HD_ / 32; ks++) {
        bf16_8 a = *(const bf16_8*)(Qp + ks * 32 + q * 8);
#pragma unroll
        for (int nt = 0; nt < 9; nt++) {
            bf16_8 bfrag = *(const bf16_8*)(&Ks[(nt * 16 + r) * KLD + ks * 32 + q * 8]);
            acc[nt] = __builtin_amdgcn_mfma_f32_16x16x32_bf16(a, bfrag, acc[nt], 0, 0, 0);
        }
    }
    float mk[9];
#pragma unroll
    for (int nt = 0; nt < 9; nt++) mk[nt] = msk[nt * 16 + r];
#pragma unroll
    for (int rg = 0; rg < 4; rg++) {
        float v[9]; float mx = -1e30f;
#pragma unroll
        for (int nt = 0; nt < 9; nt++) { v[nt] = acc[nt][rg] * SCALE_ + mk[nt]; mx = fmaxf(mx, v[nt]); }
#pragma unroll
        for (int off = 1; off < 16; off <<= 1) mx = fmaxf(mx, __shfl_xor(mx, off, 64));
        float s = 0.f;
#pragma unroll
        for (int nt = 0; nt < 9; nt++) { v[nt] = __expf(v[nt] - mx); s += v[nt]; }
#pragma unroll
        for (int off = 1; off < 16; off <<= 1) s += __shfl_xor(s, off, 64);
        float inv = 1.f / s;
        int lr = lrow0 + q * 4 + rg;
#pragma unroll
        for (int nt = 0; nt < 9; nt++)
            Ps[lr * PLD + nt * 16 + r] = f2b(v[nt] * inv);
        Ps[lr * PLD + KR + r] = 0;   // zero pad cols 144..159
    }
    __syncthreads();

    // ---- phase 2: ctx = P @ V^T; waves 2m x 2n (32m x 96n each) ----
    const int wm = (wid & 1) * 32, wn = (wid >> 1) * 96;
    size_t vbase = (size_t)bh * (HD_ * KP);

    f32x4 pacc[2][6];
#pragma unroll
    for (int i = 0; i < 2; i++)
#pragma unroll
        for (int j = 0; j < 6; j++) pacc[i][j] = (f32x4){0.f, 0.f, 0.f, 0.f};

    for (int ks = 0; ks < KP / 32; ks++) {
        bf16_8 a[2], bb[6];
#pragma unroll
        for (int i = 0; i < 2; i++)
            a[i] = *(const bf16_8*)(&Ps[(wm + i * 16 + r) * PLD + ks * 32 + q * 8]);
#pragma unroll
        for (int j = 0; j < 6; j++)
            bb[j] = *(const bf16_8*)(vtb + vbase + (size_t)(wn + j * 16 + r) * KP + ks * 32 + q * 8);
#pragma unroll
        for (int i = 0; i < 2; i++)
#pragma unroll
            for (int j = 0; j < 6; j++)
                pacc[i][j] = __builtin_amdgcn_mfma_f32_16x16x32_bf16(a[i], bb[j], pacc[i][j], 0, 0, 0);
    }

#pragma unroll
    for (int i = 0; i < 2; i++) {
#pragma unroll
        for (int rg = 0; rg < 4; rg++) {
            int tl = mb * 64 + wm + i * 16 + q * 4 + rg;
            if (tl < LW) {
                size_t rowoff = (size_t)(b * LW + tl) * H_ + h * HD_;
#pragma unroll
                for (int j = 0; j < 6; j++)
                    ctx[rowoff + wn + j * 16 + r] = f2b(pacc[i][j][rg]);
            }
        }
    }
}

// ---------------- fused residual add + LayerNorm (pure bf16 stream, f32 math) ----------------
__global__ __launch_bounds__(256) void add_ln_kernel(
    unsigned short* __restrict__ xb, const unsigned short* __restrict__ res,
    const float* __restrict__ sc, const float* __restrict__ bi)
{
    __shared__ float red[4];
    int row = blockIdx.x;
    int tid = threadIdx.x;
    size_t base = (size_t)row * H_;
    float v[3];
    float sum = 0.f;
#pragma unroll
    for (int i = 0; i < 3; i++) {
        int c = tid + i * 256;
        float t = b2f(xb[base + c]) + b2f(res[base + c]);
        v[i] = t; sum += t;
    }
    sum = block_sum(sum, red);
    float mean = sum * (1.f / H_);
    float var = 0.f;
#pragma unroll
    for (int i = 0; i < 3; i++) { float d = v[i] - mean; var += d * d; }
    var = block_sum(var, red);
    float inv = rsqrtf(var * (1.f / H_) + EPS_);
#pragma unroll
    for (int i = 0; i < 3; i++) {
        int c = tid + i * 256;
        xb[base + c] = f2b((v[i] - mean) * inv * sc[c] + bi[c]);
    }
}

// ---------------- classifier + pooled copy (32 blocks x 6 waves, bf16 in) ----------------
__global__ __launch_bounds__(384) void cls_kernel(
    const unsigned short* __restrict__ xb,
    const float* __restrict__ cls_w, const float* __restrict__ cls_b,
    float* __restrict__ out)
{
    int b = blockIdx.x;
    int tid = threadIdx.x;
    const unsigned short* p = &xb[((size_t)b * LW) * H_];
    for (int c = tid; c < H_; c += 384) out[B_ * NLAB_ + b * H_ + c] = b2f(p[c]);
    int w = tid >> 6, lane = tid & 63;
    if (w < NLAB_) {
        const float* wv = &cls_w[w * H_];
        float acc = 0.f;
#pragma unroll
        for (int i = 0; i < H_ / 64; i++) {
            int c = lane + i * 64;
            acc += b2f(p[c]) * wv[c];
        }
        acc = wave_sum(acc);
        if (lane == 0) out[b * NLAB_ + w] = acc + cls_b[w];
    }
}

extern "C" void kernel_launch(void* const* d_in, const int* in_sizes, int n_in,
                              void* d_out, int out_size, void* d_ws, size_t ws_size,
                              hipStream_t stream) {
    const float* hidden = (const float*)d_in[0];
    const int*   wti    = (const int*)d_in[1];
    const int*   gmask  = (const int*)d_in[2];
    const int*   wvalid = (const int*)d_in[3];
    const float* qkv_w  = (const float*)d_in[4];
    const float* qkv_b  = (const float*)d_in[5];
    const float* out_w  = (const float*)d_in[6];
    const float* out_b  = (const float*)d_in[7];
    const float* ff1_w  = (const float*)d_in[8];
    const float* ff1_b  = (const float*)d_in[9];
    const float* ff2_w  = (const float*)d_in[10];
    const float* ff2_b  = (const float*)d_in[11];
    const float* ln1_s  = (const float*)d_in[12];
    const float* ln1_b  = (const float*)d_in[13];
    const float* ln2_s  = (const float*)d_in[14];
    const float* ln2_b  = (const float*)d_in[15];
    const float* cls_w  = (const float*)d_in[16];
    const float* cls_b  = (const float*)d_in[17];
    float* out = (float*)d_out;

    // workspace (all bf16): ~62 MB
    const size_t XSZ = (size_t)MPAD * H_;             // 3,244,032
    const size_t ASZ = (size_t)128 * TP * KP;         // 3,932,160
    unsigned short* U    = (unsigned short*)d_ws;     // ASZ region: vtb during attn; tmpb after
    unsigned short* vtb  = U;
    unsigned short* tmpb = U;                         // lifetimes disjoint
    unsigned short* xb   = U + ASZ;                   // XSZ
    unsigned short* ctxb = xb + XSZ;                  // XSZ
    unsigned short* qkvb = ctxb + XSZ;                // 3*XSZ (aliased: h1 MPAD*FF)
    unsigned short* wb   = qkvb + (size_t)MPAD * 3 * H_;     // 2*WL_SZ (both layers)

    build_x_kernel<<<dim3(LW + 3, B_), 256, 0, stream>>>(hidden, wti, gmask, wvalid, xb);
    cvt_all_kernel<<<2 * WL_SZ / 4 / 256, 256, 0, stream>>>(
        (const float4*)qkv_w, (const float4*)out_w,
        (const float4*)ff1_w, (const float4*)ff2_w, (ushort4*)wb);

    const int GM = MPAD / 64;   // 66 m-blocks
    for (int l = 0; l < NL_; l++) {
        unsigned short* wbl = wb + (size_t)l * WL_SZ;
        // qkv = x @ qkv_w^T + b -> bf16  (generic swizzle now works for 1188 blocks)
        gemm_mfma<64, 128, 64, 0, 1, 1><<<dim3(3 * H_ / 128, GM), 256, 0, stream>>>(
            xb, wbl, qkv_b + (size_t)l * 3 * H_, qkvb, 3 * H_, H_);
        // attention: V-transpose, fused scores+softmax+PV
        vt_kernel<<<128, 256, 0, stream>>>(qkvb, vtb);
        attn_fused_kernel<<<dim3(3, 128), 256, 0, stream>>>(qkvb, wvalid, vtb, ctxb);
        // attn out-proj -> bf16 tmp  (LDS GEMM — R8's direct-from-L2 was 2x slower)
        gemm_mfma<64, 64, 64, 0, 1, 1><<<dim3(H_ / 64, GM), 256, 0, stream>>>(
            ctxb, wbl + QW_SZ, out_b + (size_t)l * H_, tmpb, H_, H_);
        add_ln_kernel<<<M_, 256, 0, stream>>>(xb, tmpb,
            ln1_s + (size_t)l * H_, ln1_b + (size_t)l * H_);
        // h1 = relu(x @ ff1_w^T + b) -> bf16
        gemm_mfma<64, 128, 64, 1, 1, 1><<<dim3(FF_ / 128, GM), 256, 0, stream>>>(
            xb, wbl + QW_SZ + OW_SZ, ff1_b + (size_t)l * FF_, qkvb, FF_, H_);
        // ff2 -> bf16 tmp: BM=128 halves B-panel re-reads (L2 traffic 726->462 MB)
        gemm_mfma<128, 64, 64, 0, 1, 1><<<dim3(H_ / 64, MPAD / 128), 256, 0, stream>>>(
            qkvb, wbl + QW_SZ + OW_SZ + F1_SZ, ff2_b + (size_t)l * H_, tmpb, H_, FF_);
        add_ln_kernel<<<M_, 256, 0, stream>>>(xb, tmpb,
            ln2_s + (size_t)l * H_, ln2_b + (size_t)l * H_);
    }
    cls_kernel<<<B_, 384, 0, stream>>>(xb, cls_w, cls_b, out);
    (void)in_sizes; (void)n_in; (void)out_size; (void)ws_size;
}

// Round 10
// 417.238 us; speedup vs baseline: 1.1410x; 1.0407x over previous
//
#include <hip/hip_runtime.h>
#include <hip/hip_bf16.h>
#include <math.h>

// Problem constants
#define B_  32
#define S_  512
#define H_  768
#define W_  128
#define G_  4
#define LW  129          // W+1
#define NH_ 4
#define HD_ 192
#define FF_ 2048
#define NL_ 2
#define NLAB_ 6
#define M_   (B_ * LW)   // 4128 rows of x
#define MPAD 4224        // 33 * 128 — zero GEMM bounds checks
#define EPS_ 1e-5f
#define SCALE_ 0.07216878364870323f   // 1/sqrt(192)

// attention padded dims
#define TP 192           // padded query rows per (b,h)
#define KP 160           // padded key count (mult of 32)
#define KR 144           // staged key rows (9 n-tiles)
#define KLD 200          // LDS row stride for K stage (bank-friendly)
#define PLD 168          // LDS row stride for P (bank-friendly for b128 frag reads)

#define QW_SZ (3 * H_ * H_)   // 1769472
#define OW_SZ (H_ * H_)       // 589824
#define F1_SZ (FF_ * H_)      // 1572864
#define F2_SZ (H_ * FF_)      // 1572864
#define WL_SZ (QW_SZ + OW_SZ + F1_SZ + F2_SZ)  // 5505024

typedef __bf16 bf16_8 __attribute__((ext_vector_type(8)));
typedef float  f32x4  __attribute__((ext_vector_type(4)));
typedef unsigned short ushort8_t __attribute__((ext_vector_type(8)));

__device__ __forceinline__ float b2f(unsigned short u) {
    union { unsigned int i; float f; } c; c.i = ((unsigned int)u) << 16; return c.f;
}
__device__ __forceinline__ unsigned short f2b(float f) {
    union { float f; unsigned int u; } c; c.f = f;
    unsigned int u = c.u;
    return (unsigned short)((u + 0x7FFFu + ((u >> 16) & 1u)) >> 16);   // RNE
}

// ---------------- reductions ----------------
__device__ __forceinline__ float wave_sum(float v) {
#pragma unroll
    for (int off = 1; off < 64; off <<= 1) v += __shfl_xor(v, off, 64);
    return v;
}
__device__ __forceinline__ float block_sum(float v, float* red) {
    v = wave_sum(v);
    int wid = threadIdx.x >> 6, lane = threadIdx.x & 63;
    if (lane == 0) red[wid] = v;
    __syncthreads();
    float r = (red[0] + red[1]) + (red[2] + red[3]);
    __syncthreads();
    return r;
}

// ---------------- gather + masked mean pool -> xb bf16 (incl. pad-row zeroing) ----------------
__global__ __launch_bounds__(256) void build_x_kernel(
    const float* __restrict__ hidden,   // (B,S,H)
    const int*   __restrict__ wti,      // (B,W,G)
    const int*   __restrict__ gmask,    // (B,W,G) bool as int32
    const int*   __restrict__ wvalid,   // (B,W)   bool as int32
    unsigned short* __restrict__ xb)    // (MPAD,H) bf16
{
    int t = blockIdx.x;     // 0..LW+2  (last 3 per batch: pad rows)
    int b = blockIdx.y;     // 0..B-1
    int tid = threadIdx.x;
    if (t >= LW) {
        int pr = M_ + b * 3 + (t - LW);
        size_t xo = (size_t)pr * H_;
#pragma unroll
        for (int i = 0; i < 3; i++) xb[xo + tid + i * 256] = 0;
        return;
    }
    size_t xo = ((size_t)b * LW + t) * H_;
    if (t == 0) {
        const float* src = hidden + (size_t)b * S_ * H_;   // token 0
#pragma unroll
        for (int i = 0; i < 3; i++) xb[xo + tid + i * 256] = f2b(src[tid + i * 256]);
    } else {
        int w = t - 1;
        int valid = wvalid[b * W_ + w];
        int ids[G_]; float msk[G_]; float cnt = 0.f;
#pragma unroll
        for (int g = 0; g < G_; g++) {
            ids[g] = wti[(b * W_ + w) * G_ + g];
            msk[g] = (gmask[(b * W_ + w) * G_ + g] != 0) ? 1.f : 0.f;
            cnt += msk[g];
        }
        float inv = valid ? (1.f / fmaxf(cnt, 1.f)) : 0.f;
#pragma unroll
        for (int i = 0; i < 3; i++) {
            int c = tid + i * 256;
            float a = 0.f;
#pragma unroll
            for (int g = 0; g < G_; g++)
                a += msk[g] * hidden[((size_t)b * S_ + ids[g]) * H_ + c];
            xb[xo + c] = f2b(a * inv);
        }
    }
}

// ---------------- weight fp32 -> bf16 (both layers, one kernel) ----------------
__global__ __launch_bounds__(256) void cvt_all_kernel(
    const float4* __restrict__ qw, const float4* __restrict__ ow,
    const float4* __restrict__ f1, const float4* __restrict__ f2,
    ushort4* __restrict__ dst)
{
    constexpr int WL4 = WL_SZ / 4;
    int i = blockIdx.x * 256 + threadIdx.x;   // 0 .. 2*WL4
    int l = (i < WL4) ? 0 : 1;
    int j = i - l * WL4;
    float4 v;
    if (j < QW_SZ / 4)                          v = qw[l * (QW_SZ / 4) + j];
    else if (j < (QW_SZ + OW_SZ) / 4)           v = ow[l * (OW_SZ / 4) + j - QW_SZ / 4];
    else if (j < (QW_SZ + OW_SZ + F1_SZ) / 4)   v = f1[l * (F1_SZ / 4) + j - (QW_SZ + OW_SZ) / 4];
    else                                        v = f2[l * (F2_SZ / 4) + j - (QW_SZ + OW_SZ + F1_SZ) / 4];
    ushort4 o; o.x = f2b(v.x); o.y = f2b(v.y); o.z = f2b(v.z); o.w = f2b(v.w);
    dst[i] = o;
}

// ---------------- LDS-staged bf16 MFMA GEMM ----------------
// XOR chunk swizzle (R6-verified) + XCD-band remap (identical to R6/R7 for %8 grids).
template <int BM, int BN, int BK, int RELU, int OUTBF, int SWZ>
__global__ __launch_bounds__(256) void gemm_mfma(
    const unsigned short* __restrict__ A,   // (MPAD,K) bf16
    const unsigned short* __restrict__ Bw,  // (N,K) bf16
    const float* __restrict__ bias,         // (N) f32
    void* __restrict__ Cout,                // (MPAD,N) f32 or bf16
    int N, int K)
{
    constexpr int MI  = BM / 32;
    constexpr int NJ  = BN / 32;
    constexpr int CPR = BK / 8;
    constexpr int RPL = 2048 / BK;
    constexpr int SA  = BM * BK / 2048;
    constexpr int SB  = BN * BK / 2048;

    __shared__ __align__(16) unsigned short As[BM * BK];
    __shared__ __align__(16) unsigned short Bs[BN * BK];

    const int tid  = threadIdx.x;
    const int lane = tid & 63;
    const int wid  = tid >> 6;

    int bx = blockIdx.x, by = blockIdx.y;
    if (SWZ) {
        int nx = gridDim.x;
        int total = nx * gridDim.y;              // must be % 8 == 0
        int id = by * nx + bx;
        int id2 = (id & 7) * (total >> 3) + (id >> 3);
        by = id2 / nx; bx = id2 - by * nx;
    }
    const int bm = by * BM;
    const int bn = bx * BN;

    const int wm = (wid & 1) * (BM / 2);
    const int wn = (wid >> 1) * (BN / 2);
    const int r  = lane & 15;
    const int q8 = lane >> 4;
    const int m8 = r & (CPR - 1);

    const int srow = tid / CPR;
    const int scol = (tid % CPR) ^ (srow & (CPR - 1));
    const unsigned short* Ag = A  + (size_t)(bm + srow) * K + scol * 8;
    const unsigned short* Bg = Bw + (size_t)(bn + srow) * K + scol * 8;

    const bf16_8* Af = (const bf16_8*)As;
    const bf16_8* Bf = (const bf16_8*)Bs;
    int arow[MI], brow[NJ];
#pragma unroll
    for (int i = 0; i < MI; i++) arow[i] = (wm + i * 16 + r) * CPR;
#pragma unroll
    for (int j = 0; j < NJ; j++) brow[j] = (wn + j * 16 + r) * CPR;

    f32x4 acc[MI][NJ];
#pragma unroll
    for (int i = 0; i < MI; i++)
#pragma unroll
        for (int j = 0; j < NJ; j++) acc[i][j] = (f32x4){0.f, 0.f, 0.f, 0.f};

    for (int k0 = 0; k0 < K; k0 += BK) {
#pragma unroll
        for (int s = 0; s < SA; s++)
            __builtin_amdgcn_global_load_lds(
                (const __attribute__((address_space(1))) void*)(Ag + (size_t)(s * RPL) * K + k0),
                (__attribute__((address_space(3))) void*)(As + s * 2048 + tid * 8), 16, 0, 0);
#pragma unroll
        for (int s = 0; s < SB; s++)
            __builtin_amdgcn_global_load_lds(
                (const __attribute__((address_space(1))) void*)(Bg + (size_t)(s * RPL) * K + k0),
                (__attribute__((address_space(3))) void*)(Bs + s * 2048 + tid * 8), 16, 0, 0);
        __syncthreads();
#pragma unroll
        for (int ks = 0; ks < BK / 32; ks++) {
            const int cc = (ks * 4 + q8) ^ m8;
            bf16_8 a[MI], b[NJ];
#pragma unroll
            for (int i = 0; i < MI; i++) a[i] = Af[arow[i] + cc];
#pragma unroll
            for (int j = 0; j < NJ; j++) b[j] = Bf[brow[j] + cc];
#pragma unroll
            for (int i = 0; i < MI; i++)
#pragma unroll
                for (int j = 0; j < NJ; j++)
                    acc[i][j] = __builtin_amdgcn_mfma_f32_16x16x32_bf16(a[i], b[j], acc[i][j], 0, 0, 0);
        }
        __syncthreads();
    }

    int col[NJ]; float bv[NJ];
#pragma unroll
    for (int j = 0; j < NJ; j++) { col[j] = bn + wn + j * 16 + r; bv[j] = bias[col[j]]; }
    const int row0 = bm + wm + ((lane >> 4) << 2);
#pragma unroll
    for (int i = 0; i < MI; i++) {
#pragma unroll
        for (int rg = 0; rg < 4; rg++) {
            size_t rowoff = (size_t)(row0 + i * 16 + rg) * N;
#pragma unroll
            for (int j = 0; j < NJ; j++) {
                float v = acc[i][j][rg] + bv[j];
                if (RELU) v = fmaxf(v, 0.f);
                if (OUTBF) ((unsigned short*)Cout)[rowoff + col[j]] = f2b(v);
                else       ((float*)Cout)[rowoff + col[j]] = v;
            }
        }
    }
}

// ---------------- V transpose: qkvb V-third -> Vt[bh][192][KP] bf16 (zero-padded) ----------------
__global__ __launch_bounds__(256) void vt_kernel(
    const unsigned short* __restrict__ qkv,  // (MPAD, 3H)
    unsigned short* __restrict__ vtb)        // (128, HD_, KP)
{
    __shared__ __align__(16) unsigned short Vs[KR * KLD];
    int bh = blockIdx.x;
    int b = bh >> 2, h = bh & 3;
    int tid = threadIdx.x;
    for (int c = tid; c < KR * 24; c += 256) {
        int t = c / 24, j = c - t * 24;
        ushort8_t v = (ushort8_t){0,0,0,0,0,0,0,0};
        if (t < LW)
            v = *(const ushort8_t*)(qkv + (size_t)(b * LW + t) * (3 * H_) + 2 * H_ + h * HD_ + j * 8);
        *(ushort8_t*)(&Vs[t * KLD + j * 8]) = v;
    }
    __syncthreads();
    size_t obase = (size_t)bh * (HD_ * KP);
    for (int c = tid; c < HD_ * (KP / 4); c += 256) {
        int d = c / (KP / 4), t0 = (c - d * (KP / 4)) * 4;
        ushort4 o;
        o.x = (t0 + 0 < KR) ? Vs[(t0 + 0) * KLD + d] : 0;
        o.y = (t0 + 1 < KR) ? Vs[(t0 + 1) * KLD + d] : 0;
        o.z = (t0 + 2 < KR) ? Vs[(t0 + 2) * KLD + d] : 0;
        o.w = (t0 + 3 < KR) ? Vs[(t0 + 3) * KLD + d] : 0;
        *(ushort4*)(&vtb[obase + (size_t)d * KP + t0]) = o;
    }
}

// ---------------- fused scores+softmax+PV: P stays in LDS ----------------
__global__ __launch_bounds__(256) void attn_fused_kernel(
    const unsigned short* __restrict__ qkv,   // (MPAD, 3H)
    const int*            __restrict__ wvalid,
    const unsigned short* __restrict__ vtb,   // (128, HD_, KP)
    unsigned short*       __restrict__ ctx)   // (MPAD, H)
{
    __shared__ __align__(16) unsigned short Ks[KR * KLD];
    __shared__ __align__(16) unsigned short Ps[64 * PLD];
    __shared__ float msk[KR];
    int mb = blockIdx.x;          // 0..2
    int bh = blockIdx.y;
    int b = bh >> 2, h = bh & 3;
    int tid = threadIdx.x, lane = tid & 63, wid = tid >> 6;
    int q = lane >> 4, r = lane & 15;

    for (int c = tid; c < KR * 24; c += 256) {
        int t = c / 24, j = c - t * 24;
        ushort8_t v = (ushort8_t){0,0,0,0,0,0,0,0};
        if (t < LW)
            v = *(const ushort8_t*)(qkv + (size_t)(b * LW + t) * (3 * H_) + H_ + h * HD_ + j * 8);
        *(ushort8_t*)(&Ks[t * KLD + j * 8]) = v;
    }
    if (tid < KR) {
        bool valid = (tid == 0) || (tid <= W_ && wvalid[b * W_ + tid - 1] != 0);
        msk[tid] = valid ? 0.f : -1e30f;
    }
    __syncthreads();

    // ---- phase 1: scores + softmax, one 16-row tile per wave ----
    const int lrow0 = wid * 16;
    const unsigned short* Qp = qkv + ((size_t)(b * LW) + mb * 64 + lrow0 + r) * (3 * H_) + h * HD_;

    f32x4 acc[9];
#pragma unroll
    for (int nt = 0; nt < 9; nt++) acc[nt] = (f32x4){0.f, 0.f, 0.f, 0.f};
    for (int ks = 0; ks < HD_ / 32; ks++) {
        bf16_8 a = *(const bf16_8*)(Qp + ks * 32 + q * 8);
#pragma unroll
        for (int nt = 0; nt < 9; nt++) {
            bf16_8 bfrag = *(const bf16_8*)(&Ks[(nt * 16 + r) * KLD + ks * 32 + q * 8]);
            acc[nt] = __builtin_amdgcn_mfma_f32_16x16x32_bf16(a, bfrag, acc[nt], 0, 0, 0);
        }
    }
    float mk[9];
#pragma unroll
    for (int nt = 0; nt < 9; nt++) mk[nt] = msk[nt * 16 + r];
#pragma unroll
    for (int rg = 0; rg < 4; rg++) {
        float v[9]; float mx = -1e30f;
#pragma unroll
        for (int nt = 0; nt < 9; nt++) { v[nt] = acc[nt][rg] * SCALE_ + mk[nt]; mx = fmaxf(mx, v[nt]); }
#pragma unroll
        for (int off = 1; off < 16; off <<= 1) mx = fmaxf(mx, __shfl_xor(mx, off, 64));
        float s = 0.f;
#pragma unroll
        for (int nt = 0; nt < 9; nt++) { v[nt] = __expf(v[nt] - mx); s += v[nt]; }
#pragma unroll
        for (int off = 1; off < 16; off <<= 1) s += __shfl_xor(s, off, 64);
        float inv = 1.f / s;
        int lr = lrow0 + q * 4 + rg;
#pragma unroll
        for (int nt = 0; nt < 9; nt++)
            Ps[lr * PLD + nt * 16 + r] = f2b(v[nt] * inv);
        Ps[lr * PLD + KR + r] = 0;   // zero pad cols 144..159
    }
    __syncthreads();

    // ---- phase 2: ctx = P @ V^T; waves 2m x 2n (32m x 96n each) ----
    const int wm = (wid & 1) * 32, wn = (wid >> 1) * 96;
    size_t vbase = (size_t)bh * (HD_ * KP);

    f32x4 pacc[2][6];
#pragma unroll
    for (int i = 0; i < 2; i++)
#pragma unroll
        for (int j = 0; j < 6; j++) pacc[i][j] = (f32x4){0.f, 0.f, 0.f, 0.f};

    for (int ks = 0; ks < KP / 32; ks++) {
        bf16_8 a[2], bb[6];
#pragma unroll
        for (int i = 0; i < 2; i++)
            a[i] = *(const bf16_8*)(&Ps[(wm + i * 16 + r) * PLD + ks * 32 + q * 8]);
#pragma unroll
        for (int j = 0; j < 6; j++)
            bb[j] = *(const bf16_8*)(vtb + vbase + (size_t)(wn + j * 16 + r) * KP + ks * 32 + q * 8);
#pragma unroll
        for (int i = 0; i < 2; i++)
#pragma unroll
            for (int j = 0; j < 6; j++)
                pacc[i][j] = __builtin_amdgcn_mfma_f32_16x16x32_bf16(a[i], bb[j], pacc[i][j], 0, 0, 0);
    }

#pragma unroll
    for (int i = 0; i < 2; i++) {
#pragma unroll
        for (int rg = 0; rg < 4; rg++) {
            int tl = mb * 64 + wm + i * 16 + q * 4 + rg;
            if (tl < LW) {
                size_t rowoff = (size_t)(b * LW + tl) * H_ + h * HD_;
#pragma unroll
                for (int j = 0; j < 6; j++)
                    ctx[rowoff + wn + j * 16 + r] = f2b(pacc[i][j][rg]);
            }
        }
    }
}

// ---------------- fused residual add + LayerNorm (pure bf16 stream, f32 math) ----------------
__global__ __launch_bounds__(256) void add_ln_kernel(
    unsigned short* __restrict__ xb, const unsigned short* __restrict__ res,
    const float* __restrict__ sc, const float* __restrict__ bi)
{
    __shared__ float red[4];
    int row = blockIdx.x;
    int tid = threadIdx.x;
    size_t base = (size_t)row * H_;
    float v[3];
    float sum = 0.f;
#pragma unroll
    for (int i = 0; i < 3; i++) {
        int c = tid + i * 256;
        float t = b2f(xb[base + c]) + b2f(res[base + c]);
        v[i] = t; sum += t;
    }
    sum = block_sum(sum, red);
    float mean = sum * (1.f / H_);
    float var = 0.f;
#pragma unroll
    for (int i = 0; i < 3; i++) { float d = v[i] - mean; var += d * d; }
    var = block_sum(var, red);
    float inv = rsqrtf(var * (1.f / H_) + EPS_);
#pragma unroll
    for (int i = 0; i < 3; i++) {
        int c = tid + i * 256;
        xb[base + c] = f2b((v[i] - mean) * inv * sc[c] + bi[c]);
    }
}

// ---------------- classifier + pooled copy (32 blocks x 6 waves, bf16 in) ----------------
__global__ __launch_bounds__(384) void cls_kernel(
    const unsigned short* __restrict__ xb,
    const float* __restrict__ cls_w, const float* __restrict__ cls_b,
    float* __restrict__ out)
{
    int b = blockIdx.x;
    int tid = threadIdx.x;
    const unsigned short* p = &xb[((size_t)b * LW) * H_];
    for (int c = tid; c < H_; c += 384) out[B_ * NLAB_ + b * H_ + c] = b2f(p[c]);
    int w = tid >> 6, lane = tid & 63;
    if (w < NLAB_) {
        const float* wv = &cls_w[w * H_];
        float acc = 0.f;
#pragma unroll
        for (int i = 0; i < H_ / 64; i++) {
            int c = lane + i * 64;
            acc += b2f(p[c]) * wv[c];
        }
        acc = wave_sum(acc);
        if (lane == 0) out[b * NLAB_ + w] = acc + cls_b[w];
    }
}

extern "C" void kernel_launch(void* const* d_in, const int* in_sizes, int n_in,
                              void* d_out, int out_size, void* d_ws, size_t ws_size,
                              hipStream_t stream) {
    const float* hidden = (const float*)d_in[0];
    const int*   wti    = (const int*)d_in[1];
    const int*   gmask  = (const int*)d_in[2];
    const int*   wvalid = (const int*)d_in[3];
    const float* qkv_w  = (const float*)d_in[4];
    const float* qkv_b  = (const float*)d_in[5];
    const float* out_w  = (const float*)d_in[6];
    const float* out_b  = (const float*)d_in[7];
    const float* ff1_w  = (const float*)d_in[8];
    const float* ff1_b  = (const float*)d_in[9];
    const float* ff2_w  = (const float*)d_in[10];
    const float* ff2_b  = (const float*)d_in[11];
    const float* ln1_s  = (const float*)d_in[12];
    const float* ln1_b  = (const float*)d_in[13];
    const float* ln2_s  = (const float*)d_in[14];
    const float* ln2_b  = (const float*)d_in[15];
    const float* cls_w  = (const float*)d_in[16];
    const float* cls_b  = (const float*)d_in[17];
    float* out = (float*)d_out;

    // workspace (all bf16): ~62 MB
    const size_t XSZ = (size_t)MPAD * H_;             // 3,244,032
    const size_t ASZ = (size_t)128 * TP * KP;         // 3,932,160
    unsigned short* U    = (unsigned short*)d_ws;     // ASZ region: vtb during attn; tmpb after
    unsigned short* vtb  = U;
    unsigned short* tmpb = U;                         // lifetimes disjoint
    unsigned short* xb   = U + ASZ;                   // XSZ
    unsigned short* ctxb = xb + XSZ;                  // XSZ
    unsigned short* qkvb = ctxb + XSZ;                // 3*XSZ (aliased: h1 MPAD*FF)
    unsigned short* wb   = qkvb + (size_t)MPAD * 3 * H_;     // 2*WL_SZ (both layers)

    build_x_kernel<<<dim3(LW + 3, B_), 256, 0, stream>>>(hidden, wti, gmask, wvalid, xb);
    cvt_all_kernel<<<2 * WL_SZ / 4 / 256, 256, 0, stream>>>(
        (const float4*)qkv_w, (const float4*)out_w,
        (const float4*)ff1_w, (const float4*)ff2_w, (ushort4*)wb);

    const int GM = MPAD / 64;   // 66 m-blocks
    for (int l = 0; l < NL_; l++) {
        unsigned short* wbl = wb + (size_t)l * WL_SZ;
        // qkv = x @ qkv_w^T + b -> bf16  (R7 config: unswizzled, 18x66 grid)
        gemm_mfma<64, 128, 64, 0, 1, 0><<<dim3(3 * H_ / 128, GM), 256, 0, stream>>>(
            xb, wbl, qkv_b + (size_t)l * 3 * H_, qkvb, 3 * H_, H_);
        // attention: V-transpose, fused scores+softmax+PV
        vt_kernel<<<128, 256, 0, stream>>>(qkvb, vtb);
        attn_fused_kernel<<<dim3(3, 128), 256, 0, stream>>>(qkvb, wvalid, vtb, ctxb);
        // attn out-proj -> bf16 tmp  (R7 config: BM=64, swizzled)
        gemm_mfma<64, 64, 64, 0, 1, 1><<<dim3(H_ / 64, GM), 256, 0, stream>>>(
            ctxb, wbl + QW_SZ, out_b + (size_t)l * H_, tmpb, H_, H_);
        add_ln_kernel<<<M_, 256, 0, stream>>>(xb, tmpb,
            ln1_s + (size_t)l * H_, ln1_b + (size_t)l * H_);
        // h1 = relu(x @ ff1_w^T + b) -> bf16  (R7 config)
        gemm_mfma<64, 128, 64, 1, 1, 1><<<dim3(FF_ / 128, GM), 256, 0, stream>>>(
            xb, wbl + QW_SZ + OW_SZ, ff1_b + (size_t)l * FF_, qkvb, FF_, H_);
        // ff2 -> bf16 tmp  (R7 config: BM=64 — R9's BM=128 starved at 1.5 blocks/CU)
        gemm_mfma<64, 64, 64, 0, 1, 1><<<dim3(H_ / 64, GM), 256, 0, stream>>>(
            qkvb, wbl + QW_SZ + OW_SZ + F1_SZ, ff2_b + (size_t)l * H_, tmpb, H_, FF_);
        add_ln_kernel<<<M_, 256, 0, stream>>>(xb, tmpb,
            ln2_s + (size_t)l * H_, ln2_b + (size_t)l * H_);
    }
    cls_kernel<<<B_, 384, 0, stream>>>(xb, cls_w, cls_b, out);
    (void)in_sizes; (void)n_in; (void)out_size; (void)ws_size;
}